// Round 6
// baseline (512.099 us; speedup 1.0000x reference)
//
#include <hip/hip_runtime.h>
#include <math.h>

#define NB 4
#define NT 2048
#define NC 1024
#define NHEADS 16
#define HDIM 64

typedef __attribute__((ext_vector_type(8))) _Float16 half8v;
typedef __attribute__((ext_vector_type(4))) float f32x4;

__device__ inline unsigned short f2h(float f) {
    _Float16 h = (_Float16)f;
    return __builtin_bit_cast(unsigned short, h);
}
__device__ inline float h2f(unsigned short u) {
    return (float)__builtin_bit_cast(_Float16, u);
}

#define AS1C(p) ((const __attribute__((address_space(1))) unsigned int*)(unsigned long long)(const void*)(p))
#define AS3P(p) ((__attribute__((address_space(3))) unsigned int*)(unsigned int)(unsigned long long)(void*)(p))
#define GLL16(gp, lp) __builtin_amdgcn_global_load_lds(AS1C(gp), AS3P(lp), 16, 0, 0)

// ---------------------------------------------------------------------------
// fp32 -> fp16 convert (vectorized)
// ---------------------------------------------------------------------------
__global__ __launch_bounds__(256) void conv_f16_kernel(
    const float* __restrict__ in, unsigned short* __restrict__ out, int n4)
{
    const int i = blockIdx.x * 256 + threadIdx.x;
    if (i >= n4) return;
    const float4 f = ((const float4*)in)[i];
    ushort4 h;
    h.x = f2h(f.x); h.y = f2h(f.y); h.z = f2h(f.z); h.w = f2h(f.w);
    ((ushort4*)out)[i] = h;
}

// ---------------------------------------------------------------------------
// Kernel 1: qkv = x @ w^T + b via fp16 MFMA (single product), fused RoPE.
// q,k written fp16 (B,NH,T,D); v written TRANSPOSED fp16 (B,NH,D,T).
// M=8192, N=3072, K=1024. Tile 128x128x32, 4 waves, 64x64 per wave.
// ---------------------------------------------------------------------------
__global__ __launch_bounds__(256) void qkv_gemm_kernel(
    const unsigned short* __restrict__ xf, const unsigned short* __restrict__ wf,
    const float* __restrict__ bias, const float* __restrict__ pe_cos,
    const float* __restrict__ pe_sin, const float* __restrict__ pe_scale,
    unsigned short* __restrict__ qb, unsigned short* __restrict__ kb,
    unsigned short* __restrict__ vtb)
{
    __shared__ __align__(16) unsigned short Ah[128 * 32];
    __shared__ __align__(16) unsigned short Bh[128 * 32];

    const int tid = threadIdx.x;
    const int w = tid >> 6, lane = tid & 63;
    const int g = lane >> 4, fr = lane & 15;
    const int wr = w >> 1, wc = w & 1;

    const int bid = blockIdx.x;                 // 1536 blocks, XCD swizzle
    const int s = (bid & 7) * 192 + (bid >> 3);
    const int m0 = (s & 63) * 128, n0 = (s >> 6) * 128;

    const int c0 = tid, c1 = tid + 256;
    const int r0 = c0 >> 2, r1 = c1 >> 2;
    const int cb0 = ((c0 & 3) * 16) ^ (((r0 >> 1) & 3) << 4);
    const int cb1 = ((c1 & 3) * 16) ^ (((r1 >> 1) & 3) << 4);
    const unsigned short* px0 = xf + (size_t)(m0 + r0) * NC + (cb0 >> 1);
    const unsigned short* px1 = xf + (size_t)(m0 + r1) * NC + (cb1 >> 1);
    const unsigned short* pw0 = wf + (size_t)(n0 + r0) * NC + (cb0 >> 1);
    const unsigned short* pw1 = wf + (size_t)(n0 + r1) * NC + (cb1 >> 1);

    f32x4 acc[4][4];
#pragma unroll
    for (int m = 0; m < 4; ++m)
#pragma unroll
        for (int n = 0; n < 4; ++n) acc[m][n] = (f32x4){0.f, 0.f, 0.f, 0.f};

    for (int k0 = 0; k0 < NC; k0 += 32) {
        __syncthreads();
        GLL16(px0 + k0, (char*)Ah + c0 * 16);
        GLL16(px1 + k0, (char*)Ah + c1 * 16);
        GLL16(pw0 + k0, (char*)Bh + c0 * 16);
        GLL16(pw1 + k0, (char*)Bh + c1 * 16);
        __syncthreads();

        half8v a_f[4], b_f[4];
#pragma unroll
        for (int m = 0; m < 4; ++m) {
            const int r = wr * 64 + m * 16 + fr;
            const int off = r * 64 + ((g * 16) ^ (((r >> 1) & 3) << 4));
            a_f[m] = *(const half8v*)((const char*)Ah + off);
        }
#pragma unroll
        for (int n = 0; n < 4; ++n) {
            const int r = wc * 64 + n * 16 + fr;
            const int off = r * 64 + ((g * 16) ^ (((r >> 1) & 3) << 4));
            b_f[n] = *(const half8v*)((const char*)Bh + off);
        }
#pragma unroll
        for (int m = 0; m < 4; ++m)
#pragma unroll
            for (int n = 0; n < 4; ++n)
                acc[m][n] = __builtin_amdgcn_mfma_f32_16x16x32_f16(a_f[m], b_f[n], acc[m][n], 0, 0, 0);
    }

    // Epilogue: bias + RoPE (+*scale q, /scale k), scatter.
#pragma unroll
    for (int n = 0; n < 4; ++n) {
        const int col = n0 + wc * 64 + n * 16 + fr;
        const int part = col >> 10;             // wave-uniform (16-col span)
        const int hh = (col & 1023) >> 6;
        const int dd = col & 63;
        const float bv = bias[col];
#pragma unroll
        for (int m = 0; m < 4; ++m) {
            const int row0 = m0 + wr * 64 + m * 16 + 4 * g;  // j: row0..row0+3
            const int bb = row0 >> 11;
            const int t0 = row0 & 2047;
            if (part < 2) {
                unsigned short* outp = (part == 0) ? qb : kb;
#pragma unroll
                for (int j = 0; j < 4; ++j) {
                    const int t = t0 + j;
                    float val = acc[m][n][j] + bv;
                    const float partner = __shfl_xor(val, 1, 64);
                    const int pidx = t * HDIM + dd;
                    const float cc = pe_cos[pidx], ss = pe_sin[pidx], sc = pe_scale[pidx];
                    const float r = (dd & 1) ? (val * cc + partner * ss)
                                             : (val * cc - partner * ss);
                    val = (part == 0) ? (r * sc) : (r / sc);
                    outp[(((size_t)bb * NHEADS + hh) * NT + t) * HDIM + dd] = f2h(val);
                }
            } else {
                ushort4 sv;
                sv.x = f2h(acc[m][n][0] + bv);
                sv.y = f2h(acc[m][n][1] + bv);
                sv.z = f2h(acc[m][n][2] + bv);
                sv.w = f2h(acc[m][n][3] + bv);
                *(ushort4*)&vtb[(((size_t)bb * NHEADS + hh) * HDIM + dd) * NT + t0] = sv;
            }
        }
    }
}

// ---------------------------------------------------------------------------
// Kernel 2: flash attention, fp16 MFMA. 1 block = (b,h,256 q-rows), 4 waves,
// each wave owns 64 q-rows -> each K/V LDS fragment feeds 4 MFMAs.
// Q in registers (direct global load, no LDS). K/Vt staged once per block
// (row-XOR swizzle). mask read as fp16. Defer-max per m-tile; li per-lane
// partial reduced once at the end.
// ---------------------------------------------------------------------------
__global__ __launch_bounds__(256, 2) void attn_mfma_kernel(
    const unsigned short* __restrict__ qb, const unsigned short* __restrict__ kb,
    const unsigned short* __restrict__ vtb, const unsigned short* __restrict__ m16,
    float* __restrict__ out)
{
    __shared__ __align__(16) unsigned short Ks[64 * 64];
    __shared__ __align__(16) unsigned short Vs[64 * 64];
    __shared__ __align__(16) unsigned short Ps[4][64 * 64];

    const int tid = threadIdx.x;
    const int w = tid >> 6, lane = tid & 63;
    const int g = lane >> 4, fr = lane & 15;

    const int bid = blockIdx.x;                  // 512 blocks, XCD swizzle
    const int s = (bid & 7) * 64 + (bid >> 3);
    const int q0 = (s & 7) * 256;
    const int h = (s >> 3) & 15;
    const int b = s >> 7;

    const size_t bh = (size_t)b * NHEADS + h;
    const unsigned short* qp = qb + (bh * NT + q0 + w * 64) * HDIM;
    const unsigned short* kp = kb + bh * NT * HDIM;
    const unsigned short* vtp = vtb + bh * HDIM * NT;
    const unsigned short* mp = m16 + ((size_t)b * NT + q0 + w * 64) * NT;

    // Q fragments direct from global: row = m*16+fr, k = kk*32+g*8
    half8v qf[4][2];
#pragma unroll
    for (int m = 0; m < 4; ++m)
#pragma unroll
        for (int kk = 0; kk < 2; ++kk)
            qf[m][kk] = *(const half8v*)(qp + (m * 16 + fr) * HDIM + kk * 32 + g * 8);

    f32x4 acc[4][4];
    float li[4][4], mi[4][4];
#pragma unroll
    for (int m = 0; m < 4; ++m)
#pragma unroll
        for (int j = 0; j < 4; ++j) {
            li[m][j] = 0.f; mi[m][j] = -3.0e38f;
            acc[m][j] = (f32x4){0.f, 0.f, 0.f, 0.f};
        }
    const float scl = 0.08838834764831845f;  // 1/sqrt(2*D)

    for (int kt = 0; kt < NT / 64; ++kt) {
        __syncthreads();
        {
            const unsigned short* ktp = kp + kt * 64 * HDIM;
#pragma unroll
            for (int half = 0; half < 2; ++half) {
                const int c = tid + half * 256;
                const int r = c >> 3;                       // K: key row; Vt: d row
                const int cb = ((c & 7) * 16) ^ ((r & 7) << 4);
                GLL16(ktp + r * HDIM + (cb >> 1), (char*)Ks + c * 16);
                GLL16(vtp + (size_t)r * NT + kt * 64 + (cb >> 1), (char*)Vs + c * 16);
            }
        }
        __syncthreads();

        // K fragments once, reused by all 4 m-tiles
        half8v kf[4][2];
#pragma unroll
        for (int nt = 0; nt < 4; ++nt) {
            const int r = nt * 16 + fr;
#pragma unroll
            for (int kk = 0; kk < 2; ++kk) {
                const int off = r * 128 + ((kk * 64 + g * 16) ^ ((r & 7) << 4));
                kf[nt][kk] = *(const half8v*)((const char*)Ks + off);
            }
        }

#pragma unroll
        for (int m = 0; m < 4; ++m) {
            // S = Q K^T for 16 q-rows (row = m*16+4g+j, col = nt*16+fr)
            f32x4 Sm[4];
#pragma unroll
            for (int nt = 0; nt < 4; ++nt) {
                Sm[nt] = (f32x4){0.f, 0.f, 0.f, 0.f};
#pragma unroll
                for (int kk = 0; kk < 2; ++kk)
                    Sm[nt] = __builtin_amdgcn_mfma_f32_16x16x32_f16(qf[m][kk], kf[nt][kk], Sm[nt], 0, 0, 0);
            }

            float sv[4][4], rmj[4];
#pragma unroll
            for (int j = 0; j < 4; ++j) {
                const unsigned short* mrow =
                    mp + (size_t)(m * 16 + 4 * g + j) * NT + kt * 64 + fr;
#pragma unroll
                for (int nt = 0; nt < 4; ++nt)
                    sv[j][nt] = fmaf(Sm[nt][j], scl, h2f(mrow[nt * 16]));
                rmj[j] = fmaxf(fmaxf(sv[j][0], sv[j][1]), fmaxf(sv[j][2], sv[j][3]));
            }

            const float worst = fmaxf(fmaxf(rmj[0] - mi[m][0], rmj[1] - mi[m][1]),
                                      fmaxf(rmj[2] - mi[m][2], rmj[3] - mi[m][3]));
            if (!__all(worst <= 8.f)) {
#pragma unroll
                for (int j = 0; j < 4; ++j) {
                    float rm = rmj[j];
                    rm = fmaxf(rm, __shfl_xor(rm, 1, 64));
                    rm = fmaxf(rm, __shfl_xor(rm, 2, 64));
                    rm = fmaxf(rm, __shfl_xor(rm, 4, 64));
                    rm = fmaxf(rm, __shfl_xor(rm, 8, 64));
                    const float mnew = fmaxf(mi[m][j], rm);
                    const float alpha = __expf(mi[m][j] - mnew);
                    li[m][j] *= alpha;
#pragma unroll
                    for (int dt = 0; dt < 4; ++dt) acc[m][dt][j] *= alpha;
                    mi[m][j] = mnew;
                }
            }

#pragma unroll
            for (int j = 0; j < 4; ++j) {
                const int prow = m * 16 + 4 * g + j;
                float ps = 0.f;
#pragma unroll
                for (int nt = 0; nt < 4; ++nt) {
                    const float p = __expf(sv[j][nt] - mi[m][j]);
                    const int off = prow * 128 + ((nt * 32 + fr * 2) ^ ((prow & 7) << 4));
                    *(unsigned short*)((char*)Ps[w] + off) = f2h(p);
                    ps += p;
                }
                li[m][j] += ps;
            }
        }

        // PV: V fragments once, reused by all 4 m-tiles
        half8v vf[4][2];
#pragma unroll
        for (int dt = 0; dt < 4; ++dt) {
            const int d = dt * 16 + fr;
#pragma unroll
            for (int kk = 0; kk < 2; ++kk) {
                const int off = d * 128 + ((kk * 64 + g * 16) ^ ((d & 7) << 4));
                vf[dt][kk] = *(const half8v*)((const char*)Vs + off);
            }
        }
#pragma unroll
        for (int m = 0; m < 4; ++m) {
            half8v pf[2];
#pragma unroll
            for (int kk = 0; kk < 2; ++kk) {
                const int off = (m * 16 + fr) * 128 + ((kk * 64 + g * 16) ^ ((fr & 7) << 4));
                pf[kk] = *(const half8v*)((const char*)Ps[w] + off);
            }
#pragma unroll
            for (int dt = 0; dt < 4; ++dt)
#pragma unroll
                for (int kk = 0; kk < 2; ++kk)
                    acc[m][dt] = __builtin_amdgcn_mfma_f32_16x16x32_f16(pf[kk], vf[dt][kk], acc[m][dt], 0, 0, 0);
        }
    }

    // final cross-lane li reduce (once), then epilogue
#pragma unroll
    for (int m = 0; m < 4; ++m)
#pragma unroll
        for (int j = 0; j < 4; ++j) {
            float lt = li[m][j];
            lt += __shfl_xor(lt, 1, 64);
            lt += __shfl_xor(lt, 2, 64);
            lt += __shfl_xor(lt, 4, 64);
            lt += __shfl_xor(lt, 8, 64);
            const float inv = 1.f / lt;
            const int t = q0 + w * 64 + m * 16 + 4 * g + j;
            float* op = out + (((size_t)b * NT + t) * NHEADS + h) * HDIM;
#pragma unroll
            for (int dt = 0; dt < 4; ++dt) op[dt * 16 + fr] = acc[m][dt][j] * inv;
        }
}

extern "C" void kernel_launch(void* const* d_in, const int* in_sizes, int n_in,
                              void* d_out, int out_size, void* d_ws, size_t ws_size,
                              hipStream_t stream) {
    const float* x        = (const float*)d_in[0];
    const float* pe_cos   = (const float*)d_in[1];
    const float* pe_sin   = (const float*)d_in[2];
    const float* pe_scale = (const float*)d_in[3];
    const float* mask     = (const float*)d_in[4];
    const float* w_qkv    = (const float*)d_in[5];
    const float* b_qkv    = (const float*)d_in[6];
    float* out = (float*)d_out;

    unsigned short* ws = (unsigned short*)d_ws;
    const size_t PER = (size_t)NB * NHEADS * NT * HDIM;   // 8388608
    unsigned short* qbuf = ws;
    unsigned short* kbuf = ws + PER;
    unsigned short* vtbuf = ws + 2 * PER;
    unsigned short* xbuf = ws + 3 * PER;                  // fp16 x (GEMM only)
    unsigned short* wbuf = xbuf + (size_t)NB * NT * NC;   // fp16 w (GEMM only)
    unsigned short* maskbuf = ws + 3 * PER;               // fp16 mask (after GEMM,
                                                          // reuses x/w region)

    conv_f16_kernel<<<8192, 256, 0, stream>>>(x, xbuf, (NB * NT * NC) / 4);
    conv_f16_kernel<<<3072, 256, 0, stream>>>(w_qkv, wbuf, (3 * NC * NC) / 4);
    qkv_gemm_kernel<<<1536, 256, 0, stream>>>(xbuf, wbuf, b_qkv,
                                              pe_cos, pe_sin, pe_scale,
                                              qbuf, kbuf, vtbuf);
    conv_f16_kernel<<<16384, 256, 0, stream>>>(mask, maskbuf, (NB * NT * NT) / 4);
    attn_mfma_kernel<<<512, 256, 0, stream>>>(qbuf, kbuf, vtbuf, maskbuf, out);
}

// Round 7
// 273.425 us; speedup vs baseline: 1.8729x; 1.8729x over previous
//
#include <hip/hip_runtime.h>
#include <math.h>

#define NB 4
#define NT 2048
#define NC 1024
#define NHEADS 16
#define HDIM 64

typedef __attribute__((ext_vector_type(8))) _Float16 half8v;
typedef __attribute__((ext_vector_type(4))) float f32x4;

__device__ inline unsigned short f2h(float f) {
    _Float16 h = (_Float16)f;
    return __builtin_bit_cast(unsigned short, h);
}
__device__ inline float h2f(unsigned short u) {
    return (float)__builtin_bit_cast(_Float16, u);
}

#define AS1C(p) ((const __attribute__((address_space(1))) unsigned int*)(unsigned long long)(const void*)(p))
#define AS3P(p) ((__attribute__((address_space(3))) unsigned int*)(unsigned int)(unsigned long long)(void*)(p))
#define GLL16(gp, lp) __builtin_amdgcn_global_load_lds(AS1C(gp), AS3P(lp), 16, 0, 0)

// ---------------------------------------------------------------------------
// fp32 -> fp16 convert (vectorized)
// ---------------------------------------------------------------------------
__global__ __launch_bounds__(256) void conv_f16_kernel(
    const float* __restrict__ in, unsigned short* __restrict__ out, int n4)
{
    const int i = blockIdx.x * 256 + threadIdx.x;
    if (i >= n4) return;
    const float4 f = ((const float4*)in)[i];
    ushort4 h;
    h.x = f2h(f.x); h.y = f2h(f.y); h.z = f2h(f.z); h.w = f2h(f.w);
    ((ushort4*)out)[i] = h;
}

// ---------------------------------------------------------------------------
// Kernel 1: qkv = x @ w^T + b via fp16 MFMA (single product), fused RoPE.
// q,k written fp16 (B,NH,T,D); v written TRANSPOSED fp16 (B,NH,D,T).
// M=8192, N=3072, K=1024. Tile 128x128x32, 4 waves, 64x64 per wave.
// ---------------------------------------------------------------------------
__global__ __launch_bounds__(256) void qkv_gemm_kernel(
    const unsigned short* __restrict__ xf, const unsigned short* __restrict__ wf,
    const float* __restrict__ bias, const float* __restrict__ pe_cos,
    const float* __restrict__ pe_sin, const float* __restrict__ pe_scale,
    unsigned short* __restrict__ qb, unsigned short* __restrict__ kb,
    unsigned short* __restrict__ vtb)
{
    __shared__ __align__(16) unsigned short Ah[128 * 32];
    __shared__ __align__(16) unsigned short Bh[128 * 32];

    const int tid = threadIdx.x;
    const int w = tid >> 6, lane = tid & 63;
    const int g = lane >> 4, fr = lane & 15;
    const int wr = w >> 1, wc = w & 1;

    const int bid = blockIdx.x;                 // 1536 blocks, XCD swizzle
    const int s = (bid & 7) * 192 + (bid >> 3);
    const int m0 = (s & 63) * 128, n0 = (s >> 6) * 128;

    const int c0 = tid, c1 = tid + 256;
    const int r0 = c0 >> 2, r1 = c1 >> 2;
    const int cb0 = ((c0 & 3) * 16) ^ (((r0 >> 1) & 3) << 4);
    const int cb1 = ((c1 & 3) * 16) ^ (((r1 >> 1) & 3) << 4);
    const unsigned short* px0 = xf + (size_t)(m0 + r0) * NC + (cb0 >> 1);
    const unsigned short* px1 = xf + (size_t)(m0 + r1) * NC + (cb1 >> 1);
    const unsigned short* pw0 = wf + (size_t)(n0 + r0) * NC + (cb0 >> 1);
    const unsigned short* pw1 = wf + (size_t)(n0 + r1) * NC + (cb1 >> 1);

    f32x4 acc[4][4];
#pragma unroll
    for (int m = 0; m < 4; ++m)
#pragma unroll
        for (int n = 0; n < 4; ++n) acc[m][n] = (f32x4){0.f, 0.f, 0.f, 0.f};

    for (int k0 = 0; k0 < NC; k0 += 32) {
        __syncthreads();
        GLL16(px0 + k0, (char*)Ah + c0 * 16);
        GLL16(px1 + k0, (char*)Ah + c1 * 16);
        GLL16(pw0 + k0, (char*)Bh + c0 * 16);
        GLL16(pw1 + k0, (char*)Bh + c1 * 16);
        __syncthreads();

        half8v a_f[4], b_f[4];
#pragma unroll
        for (int m = 0; m < 4; ++m) {
            const int r = wr * 64 + m * 16 + fr;
            const int off = r * 64 + ((g * 16) ^ (((r >> 1) & 3) << 4));
            a_f[m] = *(const half8v*)((const char*)Ah + off);
        }
#pragma unroll
        for (int n = 0; n < 4; ++n) {
            const int r = wc * 64 + n * 16 + fr;
            const int off = r * 64 + ((g * 16) ^ (((r >> 1) & 3) << 4));
            b_f[n] = *(const half8v*)((const char*)Bh + off);
        }
#pragma unroll
        for (int m = 0; m < 4; ++m)
#pragma unroll
            for (int n = 0; n < 4; ++n)
                acc[m][n] = __builtin_amdgcn_mfma_f32_16x16x32_f16(a_f[m], b_f[n], acc[m][n], 0, 0, 0);
    }

    // Epilogue: bias + RoPE (+*scale q, /scale k), scatter.
#pragma unroll
    for (int n = 0; n < 4; ++n) {
        const int col = n0 + wc * 64 + n * 16 + fr;
        const int part = col >> 10;             // wave-uniform (16-col span)
        const int hh = (col & 1023) >> 6;
        const int dd = col & 63;
        const float bv = bias[col];
#pragma unroll
        for (int m = 0; m < 4; ++m) {
            const int row0 = m0 + wr * 64 + m * 16 + 4 * g;  // j: row0..row0+3
            const int bb = row0 >> 11;
            const int t0 = row0 & 2047;
            if (part < 2) {
                unsigned short* outp = (part == 0) ? qb : kb;
#pragma unroll
                for (int j = 0; j < 4; ++j) {
                    const int t = t0 + j;
                    float val = acc[m][n][j] + bv;
                    const float partner = __shfl_xor(val, 1, 64);
                    const int pidx = t * HDIM + dd;
                    const float cc = pe_cos[pidx], ss = pe_sin[pidx], sc = pe_scale[pidx];
                    const float r = (dd & 1) ? (val * cc + partner * ss)
                                             : (val * cc - partner * ss);
                    val = (part == 0) ? (r * sc) : (r / sc);
                    outp[(((size_t)bb * NHEADS + hh) * NT + t) * HDIM + dd] = f2h(val);
                }
            } else {
                ushort4 sv;
                sv.x = f2h(acc[m][n][0] + bv);
                sv.y = f2h(acc[m][n][1] + bv);
                sv.z = f2h(acc[m][n][2] + bv);
                sv.w = f2h(acc[m][n][3] + bv);
                *(ushort4*)&vtb[(((size_t)bb * NHEADS + hh) * HDIM + dd) * NT + t0] = sv;
            }
        }
    }
}

// ---------------------------------------------------------------------------
// Kernel 2: flash attention, fp16 MFMA. 1 block = (b,h,128 q-rows), 4 waves,
// each wave owns 32 q-rows (M=2 m-tiles) -> each K/V LDS fragment feeds
// 2 MFMAs while staying within the no-spill VGPR budget (~64 persistent).
// Q in registers (direct global load). K/Vt staged per block (row-XOR
// swizzle). mask read fp16. Defer-max per m-tile; li per-lane partial.
// ---------------------------------------------------------------------------
__global__ __launch_bounds__(256) void attn_mfma_kernel(
    const unsigned short* __restrict__ qb, const unsigned short* __restrict__ kb,
    const unsigned short* __restrict__ vtb, const unsigned short* __restrict__ m16,
    float* __restrict__ out)
{
    __shared__ __align__(16) unsigned short Ks[64 * 64];
    __shared__ __align__(16) unsigned short Vs[64 * 64];
    __shared__ __align__(16) unsigned short Ps[4][32 * 64];

    const int tid = threadIdx.x;
    const int w = tid >> 6, lane = tid & 63;
    const int g = lane >> 4, fr = lane & 15;

    const int bid = blockIdx.x;                  // 1024 blocks, XCD swizzle
    const int s = (bid & 7) * 128 + (bid >> 3);
    const int q0 = (s & 15) * 128;
    const int h = (s >> 4) & 15;
    const int b = s >> 8;

    const size_t bh = (size_t)b * NHEADS + h;
    const unsigned short* qp = qb + (bh * NT + q0 + w * 32) * HDIM;
    const unsigned short* kp = kb + bh * NT * HDIM;
    const unsigned short* vtp = vtb + bh * HDIM * NT;
    const unsigned short* mp = m16 + ((size_t)b * NT + q0 + w * 32) * NT;

    // Q fragments direct from global: row = m*16+fr, k = kk*32+g*8
    half8v qf[2][2];
#pragma unroll
    for (int m = 0; m < 2; ++m)
#pragma unroll
        for (int kk = 0; kk < 2; ++kk)
            qf[m][kk] = *(const half8v*)(qp + (m * 16 + fr) * HDIM + kk * 32 + g * 8);

    f32x4 acc[2][4];
    float li[2][4], mi[2][4];
#pragma unroll
    for (int m = 0; m < 2; ++m)
#pragma unroll
        for (int j = 0; j < 4; ++j) {
            li[m][j] = 0.f; mi[m][j] = -3.0e38f;
            acc[m][j] = (f32x4){0.f, 0.f, 0.f, 0.f};
        }
    const float scl = 0.08838834764831845f;  // 1/sqrt(2*D)

    for (int kt = 0; kt < NT / 64; ++kt) {
        __syncthreads();
        {
            const unsigned short* ktp = kp + kt * 64 * HDIM;
#pragma unroll
            for (int half = 0; half < 2; ++half) {
                const int c = tid + half * 256;
                const int r = c >> 3;                       // K: key row; Vt: d row
                const int cb = ((c & 7) * 16) ^ ((r & 7) << 4);
                GLL16(ktp + r * HDIM + (cb >> 1), (char*)Ks + c * 16);
                GLL16(vtp + (size_t)r * NT + kt * 64 + (cb >> 1), (char*)Vs + c * 16);
            }
        }
        __syncthreads();

        // K fragments once, reused by both m-tiles
        half8v kf[4][2];
#pragma unroll
        for (int nt = 0; nt < 4; ++nt) {
            const int r = nt * 16 + fr;
#pragma unroll
            for (int kk = 0; kk < 2; ++kk) {
                const int off = r * 128 + ((kk * 64 + g * 16) ^ ((r & 7) << 4));
                kf[nt][kk] = *(const half8v*)((const char*)Ks + off);
            }
        }

#pragma unroll
        for (int m = 0; m < 2; ++m) {
            // S = Q K^T for 16 q-rows (row = m*16+4g+j, col = nt*16+fr)
            f32x4 Sm[4];
#pragma unroll
            for (int nt = 0; nt < 4; ++nt) {
                Sm[nt] = (f32x4){0.f, 0.f, 0.f, 0.f};
#pragma unroll
                for (int kk = 0; kk < 2; ++kk)
                    Sm[nt] = __builtin_amdgcn_mfma_f32_16x16x32_f16(qf[m][kk], kf[nt][kk], Sm[nt], 0, 0, 0);
            }

            float sv[4][4], rmj[4];
#pragma unroll
            for (int j = 0; j < 4; ++j) {
                const unsigned short* mrow =
                    mp + (size_t)(m * 16 + 4 * g + j) * NT + kt * 64 + fr;
#pragma unroll
                for (int nt = 0; nt < 4; ++nt)
                    sv[j][nt] = fmaf(Sm[nt][j], scl, h2f(mrow[nt * 16]));
                rmj[j] = fmaxf(fmaxf(sv[j][0], sv[j][1]), fmaxf(sv[j][2], sv[j][3]));
            }

            const float worst = fmaxf(fmaxf(rmj[0] - mi[m][0], rmj[1] - mi[m][1]),
                                      fmaxf(rmj[2] - mi[m][2], rmj[3] - mi[m][3]));
            if (!__all(worst <= 8.f)) {
#pragma unroll
                for (int j = 0; j < 4; ++j) {
                    float rm = rmj[j];
                    rm = fmaxf(rm, __shfl_xor(rm, 1, 64));
                    rm = fmaxf(rm, __shfl_xor(rm, 2, 64));
                    rm = fmaxf(rm, __shfl_xor(rm, 4, 64));
                    rm = fmaxf(rm, __shfl_xor(rm, 8, 64));
                    const float mnew = fmaxf(mi[m][j], rm);
                    const float alpha = __expf(mi[m][j] - mnew);
                    li[m][j] *= alpha;
#pragma unroll
                    for (int dt = 0; dt < 4; ++dt) acc[m][dt][j] *= alpha;
                    mi[m][j] = mnew;
                }
            }

#pragma unroll
            for (int j = 0; j < 4; ++j) {
                const int prow = m * 16 + 4 * g + j;
                float ps = 0.f;
#pragma unroll
                for (int nt = 0; nt < 4; ++nt) {
                    const float p = __expf(sv[j][nt] - mi[m][j]);
                    const int off = prow * 128 + ((nt * 32 + fr * 2) ^ ((prow & 7) << 4));
                    *(unsigned short*)((char*)Ps[w] + off) = f2h(p);
                    ps += p;
                }
                li[m][j] += ps;
            }
        }

        // PV: V fragments once, reused by both m-tiles
        half8v vf[4][2];
#pragma unroll
        for (int dt = 0; dt < 4; ++dt) {
            const int d = dt * 16 + fr;
#pragma unroll
            for (int kk = 0; kk < 2; ++kk) {
                const int off = d * 128 + ((kk * 64 + g * 16) ^ ((d & 7) << 4));
                vf[dt][kk] = *(const half8v*)((const char*)Vs + off);
            }
        }
#pragma unroll
        for (int m = 0; m < 2; ++m) {
            half8v pf[2];
#pragma unroll
            for (int kk = 0; kk < 2; ++kk) {
                const int off = (m * 16 + fr) * 128 + ((kk * 64 + g * 16) ^ ((fr & 7) << 4));
                pf[kk] = *(const half8v*)((const char*)Ps[w] + off);
            }
#pragma unroll
            for (int dt = 0; dt < 4; ++dt)
#pragma unroll
                for (int kk = 0; kk < 2; ++kk)
                    acc[m][dt] = __builtin_amdgcn_mfma_f32_16x16x32_f16(pf[kk], vf[dt][kk], acc[m][dt], 0, 0, 0);
        }
    }

    // final cross-lane li reduce (once), then epilogue
#pragma unroll
    for (int m = 0; m < 2; ++m)
#pragma unroll
        for (int j = 0; j < 4; ++j) {
            float lt = li[m][j];
            lt += __shfl_xor(lt, 1, 64);
            lt += __shfl_xor(lt, 2, 64);
            lt += __shfl_xor(lt, 4, 64);
            lt += __shfl_xor(lt, 8, 64);
            const float inv = 1.f / lt;
            const int t = q0 + w * 32 + m * 16 + 4 * g + j;
            float* op = out + (((size_t)b * NT + t) * NHEADS + h) * HDIM;
#pragma unroll
            for (int dt = 0; dt < 4; ++dt) op[dt * 16 + fr] = acc[m][dt][j] * inv;
        }
}

extern "C" void kernel_launch(void* const* d_in, const int* in_sizes, int n_in,
                              void* d_out, int out_size, void* d_ws, size_t ws_size,
                              hipStream_t stream) {
    const float* x        = (const float*)d_in[0];
    const float* pe_cos   = (const float*)d_in[1];
    const float* pe_sin   = (const float*)d_in[2];
    const float* pe_scale = (const float*)d_in[3];
    const float* mask     = (const float*)d_in[4];
    const float* w_qkv    = (const float*)d_in[5];
    const float* b_qkv    = (const float*)d_in[6];
    float* out = (float*)d_out;

    unsigned short* ws = (unsigned short*)d_ws;
    const size_t PER = (size_t)NB * NHEADS * NT * HDIM;   // 8388608
    unsigned short* qbuf = ws;
    unsigned short* kbuf = ws + PER;
    unsigned short* vtbuf = ws + 2 * PER;
    unsigned short* xbuf = ws + 3 * PER;                  // fp16 x (GEMM only)
    unsigned short* wbuf = xbuf + (size_t)NB * NT * NC;   // fp16 w (GEMM only)
    unsigned short* maskbuf = ws + 3 * PER;               // fp16 mask (after GEMM,
                                                          // reuses x/w region)

    conv_f16_kernel<<<8192, 256, 0, stream>>>(x, xbuf, (NB * NT * NC) / 4);
    conv_f16_kernel<<<3072, 256, 0, stream>>>(w_qkv, wbuf, (3 * NC * NC) / 4);
    qkv_gemm_kernel<<<1536, 256, 0, stream>>>(xbuf, wbuf, b_qkv,
                                              pe_cos, pe_sin, pe_scale,
                                              qbuf, kbuf, vtbuf);
    conv_f16_kernel<<<16384, 256, 0, stream>>>(mask, maskbuf, (NB * NT * NT) / 4);
    attn_mfma_kernel<<<1024, 256, 0, stream>>>(qbuf, kbuf, vtbuf, maskbuf, out);
}

// Round 8
// 260.649 us; speedup vs baseline: 1.9647x; 1.0490x over previous
//
#include <hip/hip_runtime.h>
#include <math.h>

#define NB 4
#define NT 2048
#define NC 1024
#define NHEADS 16
#define HDIM 64

typedef __attribute__((ext_vector_type(8))) _Float16 half8v;
typedef __attribute__((ext_vector_type(4))) float f32x4;

__device__ inline unsigned short f2h(float f) {
    _Float16 h = (_Float16)f;
    return __builtin_bit_cast(unsigned short, h);
}
__device__ inline float h2f(unsigned short u) {
    return (float)__builtin_bit_cast(_Float16, u);
}

#define AS1C(p) ((const __attribute__((address_space(1))) unsigned int*)(unsigned long long)(const void*)(p))
#define AS3P(p) ((__attribute__((address_space(3))) unsigned int*)(unsigned int)(unsigned long long)(void*)(p))
#define GLL16(gp, lp) __builtin_amdgcn_global_load_lds(AS1C(gp), AS3P(lp), 16, 0, 0)

// ---------------------------------------------------------------------------
// fp32 -> fp16 convert (vectorized)
// ---------------------------------------------------------------------------
__global__ __launch_bounds__(256) void conv_f16_kernel(
    const float* __restrict__ in, unsigned short* __restrict__ out, int n4)
{
    const int i = blockIdx.x * 256 + threadIdx.x;
    if (i >= n4) return;
    const float4 f = ((const float4*)in)[i];
    ushort4 h;
    h.x = f2h(f.x); h.y = f2h(f.y); h.z = f2h(f.z); h.w = f2h(f.w);
    ((ushort4*)out)[i] = h;
}

// ---------------------------------------------------------------------------
// mask fp32 -> fp16, permuted into MFMA fragment order within each 64-col
// block: out[row][kt*64 + fr*4 + nt] = in[row][kt*64 + nt*16 + fr]
// so attention lane (fr) reads its 4 nt-values as one ushort4.
// ---------------------------------------------------------------------------
__global__ __launch_bounds__(256) void mask_conv_kernel(
    const float* __restrict__ in, unsigned short* __restrict__ out)
{
    const size_t i = (size_t)blockIdx.x * 256 + threadIdx.x;  // ushort4 index
    const int row = (int)(i >> 9);        // 512 ushort4 per 2048-col row
    const int c4 = (int)(i & 511);
    const int ktb = c4 >> 4;              // 64-col block
    const int fr = c4 & 15;
    const float* ip = in + (size_t)row * NT + ktb * 64 + fr;
    ushort4 o;
    o.x = f2h(ip[0]);
    o.y = f2h(ip[16]);
    o.z = f2h(ip[32]);
    o.w = f2h(ip[48]);
    ((ushort4*)out)[i] = o;
}

// ---------------------------------------------------------------------------
// Kernel 1: qkv = x @ w^T + b via fp16 MFMA (single product), fused RoPE.
// q,k written fp16 (B,NH,T,D); v written TRANSPOSED fp16 (B,NH,D,T).
// M=8192, N=3072, K=1024. Tile 128x128x32, 4 waves, 64x64 per wave.
// ---------------------------------------------------------------------------
__global__ __launch_bounds__(256) void qkv_gemm_kernel(
    const unsigned short* __restrict__ xf, const unsigned short* __restrict__ wf,
    const float* __restrict__ bias, const float* __restrict__ pe_cos,
    const float* __restrict__ pe_sin, const float* __restrict__ pe_scale,
    unsigned short* __restrict__ qb, unsigned short* __restrict__ kb,
    unsigned short* __restrict__ vtb)
{
    __shared__ __align__(16) unsigned short Ah[128 * 32];
    __shared__ __align__(16) unsigned short Bh[128 * 32];

    const int tid = threadIdx.x;
    const int w = tid >> 6, lane = tid & 63;
    const int g = lane >> 4, fr = lane & 15;
    const int wr = w >> 1, wc = w & 1;

    const int bid = blockIdx.x;                 // 1536 blocks, XCD swizzle
    const int s = (bid & 7) * 192 + (bid >> 3);
    const int m0 = (s & 63) * 128, n0 = (s >> 6) * 128;

    const int c0 = tid, c1 = tid + 256;
    const int r0 = c0 >> 2, r1 = c1 >> 2;
    const int cb0 = ((c0 & 3) * 16) ^ (((r0 >> 1) & 3) << 4);
    const int cb1 = ((c1 & 3) * 16) ^ (((r1 >> 1) & 3) << 4);
    const unsigned short* px0 = xf + (size_t)(m0 + r0) * NC + (cb0 >> 1);
    const unsigned short* px1 = xf + (size_t)(m0 + r1) * NC + (cb1 >> 1);
    const unsigned short* pw0 = wf + (size_t)(n0 + r0) * NC + (cb0 >> 1);
    const unsigned short* pw1 = wf + (size_t)(n0 + r1) * NC + (cb1 >> 1);

    f32x4 acc[4][4];
#pragma unroll
    for (int m = 0; m < 4; ++m)
#pragma unroll
        for (int n = 0; n < 4; ++n) acc[m][n] = (f32x4){0.f, 0.f, 0.f, 0.f};

    for (int k0 = 0; k0 < NC; k0 += 32) {
        __syncthreads();
        GLL16(px0 + k0, (char*)Ah + c0 * 16);
        GLL16(px1 + k0, (char*)Ah + c1 * 16);
        GLL16(pw0 + k0, (char*)Bh + c0 * 16);
        GLL16(pw1 + k0, (char*)Bh + c1 * 16);
        __syncthreads();

        half8v a_f[4], b_f[4];
#pragma unroll
        for (int m = 0; m < 4; ++m) {
            const int r = wr * 64 + m * 16 + fr;
            const int off = r * 64 + ((g * 16) ^ (((r >> 1) & 3) << 4));
            a_f[m] = *(const half8v*)((const char*)Ah + off);
        }
#pragma unroll
        for (int n = 0; n < 4; ++n) {
            const int r = wc * 64 + n * 16 + fr;
            const int off = r * 64 + ((g * 16) ^ (((r >> 1) & 3) << 4));
            b_f[n] = *(const half8v*)((const char*)Bh + off);
        }
#pragma unroll
        for (int m = 0; m < 4; ++m)
#pragma unroll
            for (int n = 0; n < 4; ++n)
                acc[m][n] = __builtin_amdgcn_mfma_f32_16x16x32_f16(a_f[m], b_f[n], acc[m][n], 0, 0, 0);
    }

    // Epilogue: bias + RoPE (+*scale q, /scale k), scatter.
#pragma unroll
    for (int n = 0; n < 4; ++n) {
        const int col = n0 + wc * 64 + n * 16 + fr;
        const int part = col >> 10;             // wave-uniform (16-col span)
        const int hh = (col & 1023) >> 6;
        const int dd = col & 63;
        const float bv = bias[col];
#pragma unroll
        for (int m = 0; m < 4; ++m) {
            const int row0 = m0 + wr * 64 + m * 16 + 4 * g;  // j: row0..row0+3
            const int bb = row0 >> 11;
            const int t0 = row0 & 2047;
            if (part < 2) {
                unsigned short* outp = (part == 0) ? qb : kb;
#pragma unroll
                for (int j = 0; j < 4; ++j) {
                    const int t = t0 + j;
                    float val = acc[m][n][j] + bv;
                    const float partner = __shfl_xor(val, 1, 64);
                    const int pidx = t * HDIM + dd;
                    const float cc = pe_cos[pidx], ss = pe_sin[pidx], sc = pe_scale[pidx];
                    const float r = (dd & 1) ? (val * cc + partner * ss)
                                             : (val * cc - partner * ss);
                    val = (part == 0) ? (r * sc) : (r / sc);
                    outp[(((size_t)bb * NHEADS + hh) * NT + t) * HDIM + dd] = f2h(val);
                }
            } else {
                ushort4 sv;
                sv.x = f2h(acc[m][n][0] + bv);
                sv.y = f2h(acc[m][n][1] + bv);
                sv.z = f2h(acc[m][n][2] + bv);
                sv.w = f2h(acc[m][n][3] + bv);
                *(ushort4*)&vtb[(((size_t)bb * NHEADS + hh) * HDIM + dd) * NT + t0] = sv;
            }
        }
    }
}

// ---------------------------------------------------------------------------
// Kernel 2: flash attention, fp16 MFMA. 1 block = (b,h,128 q-rows), 4 waves,
// each wave owns 32 q-rows (M=2). K/Vt double-buffered in LDS (T3-lite):
// next tile's global_load_lds issued BEFORE compute, single barrier per
// iter. mask pre-permuted fp16 -> one ushort4 per (m,j). Defer-max softmax.
// ---------------------------------------------------------------------------
__global__ __launch_bounds__(256) void attn_mfma_kernel(
    const unsigned short* __restrict__ qb, const unsigned short* __restrict__ kb,
    const unsigned short* __restrict__ vtb, const unsigned short* __restrict__ m16,
    float* __restrict__ out)
{
    __shared__ __align__(16) unsigned short Ks[2][64 * 64];
    __shared__ __align__(16) unsigned short Vs[2][64 * 64];
    __shared__ __align__(16) unsigned short Ps[4][32 * 64];

    const int tid = threadIdx.x;
    const int w = tid >> 6, lane = tid & 63;
    const int g = lane >> 4, fr = lane & 15;

    const int bid = blockIdx.x;                  // 1024 blocks, XCD swizzle
    const int s = (bid & 7) * 128 + (bid >> 3);
    const int q0 = (s & 15) * 128;
    const int h = (s >> 4) & 15;
    const int b = s >> 8;

    const size_t bh = (size_t)b * NHEADS + h;
    const unsigned short* qp = qb + (bh * NT + q0 + w * 32) * HDIM;
    const unsigned short* kp = kb + bh * NT * HDIM;
    const unsigned short* vtp = vtb + bh * HDIM * NT;
    const unsigned short* mp = m16 + ((size_t)b * NT + q0 + w * 32) * NT;

    // staging helper: chunk c -> row r=c>>3, swz(r)=(r&7)<<4 bytes
    const int sc0 = tid, sc1 = tid + 256;
    const int sr0 = sc0 >> 3, scb0 = ((sc0 & 7) * 16) ^ ((sr0 & 7) << 4);
    const int sr1 = sc1 >> 3, scb1 = ((sc1 & 7) * 16) ^ ((sr1 & 7) << 4);

#define STAGE(buf, kt)                                                          \
    do {                                                                        \
        const unsigned short* ktp_ = kp + (kt) * 64 * HDIM;                     \
        GLL16(ktp_ + sr0 * HDIM + (scb0 >> 1), (char*)Ks[buf] + sc0 * 16);      \
        GLL16(vtp + (size_t)sr0 * NT + (kt) * 64 + (scb0 >> 1),                 \
              (char*)Vs[buf] + sc0 * 16);                                       \
        GLL16(ktp_ + sr1 * HDIM + (scb1 >> 1), (char*)Ks[buf] + sc1 * 16);      \
        GLL16(vtp + (size_t)sr1 * NT + (kt) * 64 + (scb1 >> 1),                 \
              (char*)Vs[buf] + sc1 * 16);                                       \
    } while (0)

    // Q fragments direct from global: row = m*16+fr, k = kk*32+g*8
    half8v qf[2][2];
#pragma unroll
    for (int m = 0; m < 2; ++m)
#pragma unroll
        for (int kk = 0; kk < 2; ++kk)
            qf[m][kk] = *(const half8v*)(qp + (m * 16 + fr) * HDIM + kk * 32 + g * 8);

    f32x4 acc[2][4];
    float li[2][4], mi[2][4];
#pragma unroll
    for (int m = 0; m < 2; ++m)
#pragma unroll
        for (int j = 0; j < 4; ++j) {
            li[m][j] = 0.f; mi[m][j] = -3.0e38f;
            acc[m][j] = (f32x4){0.f, 0.f, 0.f, 0.f};
        }
    const float scl = 0.08838834764831845f;  // 1/sqrt(2*D)

    STAGE(0, 0);
    __syncthreads();
    int cur = 0;

    for (int kt = 0; kt < NT / 64; ++kt) {
        // issue next tile's loads into the other buffer (hidden under compute)
        if (kt + 1 < NT / 64) STAGE(cur ^ 1, kt + 1);

        // K fragments once, reused by both m-tiles
        half8v kf[4][2];
#pragma unroll
        for (int nt = 0; nt < 4; ++nt) {
            const int r = nt * 16 + fr;
#pragma unroll
            for (int kk = 0; kk < 2; ++kk) {
                const int off = r * 128 + ((kk * 64 + g * 16) ^ ((r & 7) << 4));
                kf[nt][kk] = *(const half8v*)((const char*)Ks[cur] + off);
            }
        }

#pragma unroll
        for (int m = 0; m < 2; ++m) {
            // S = Q K^T for 16 q-rows (row = m*16+4g+j, col = nt*16+fr)
            f32x4 Sm[4];
#pragma unroll
            for (int nt = 0; nt < 4; ++nt) {
                Sm[nt] = (f32x4){0.f, 0.f, 0.f, 0.f};
#pragma unroll
                for (int kk = 0; kk < 2; ++kk)
                    Sm[nt] = __builtin_amdgcn_mfma_f32_16x16x32_f16(qf[m][kk], kf[nt][kk], Sm[nt], 0, 0, 0);
            }

            float sv[4][4], rmj[4];
#pragma unroll
            for (int j = 0; j < 4; ++j) {
                const ushort4 mv = *(const ushort4*)(
                    mp + (size_t)(m * 16 + 4 * g + j) * NT + kt * 64 + fr * 4);
                sv[j][0] = fmaf(Sm[0][j], scl, h2f(mv.x));
                sv[j][1] = fmaf(Sm[1][j], scl, h2f(mv.y));
                sv[j][2] = fmaf(Sm[2][j], scl, h2f(mv.z));
                sv[j][3] = fmaf(Sm[3][j], scl, h2f(mv.w));
                rmj[j] = fmaxf(fmaxf(sv[j][0], sv[j][1]), fmaxf(sv[j][2], sv[j][3]));
            }

            const float worst = fmaxf(fmaxf(rmj[0] - mi[m][0], rmj[1] - mi[m][1]),
                                      fmaxf(rmj[2] - mi[m][2], rmj[3] - mi[m][3]));
            if (!__all(worst <= 8.f)) {
#pragma unroll
                for (int j = 0; j < 4; ++j) {
                    float rm = rmj[j];
                    rm = fmaxf(rm, __shfl_xor(rm, 1, 64));
                    rm = fmaxf(rm, __shfl_xor(rm, 2, 64));
                    rm = fmaxf(rm, __shfl_xor(rm, 4, 64));
                    rm = fmaxf(rm, __shfl_xor(rm, 8, 64));
                    const float mnew = fmaxf(mi[m][j], rm);
                    const float alpha = __expf(mi[m][j] - mnew);
                    li[m][j] *= alpha;
#pragma unroll
                    for (int dt = 0; dt < 4; ++dt) acc[m][dt][j] *= alpha;
                    mi[m][j] = mnew;
                }
            }

#pragma unroll
            for (int j = 0; j < 4; ++j) {
                const int prow = m * 16 + 4 * g + j;
                float ps = 0.f;
#pragma unroll
                for (int nt = 0; nt < 4; ++nt) {
                    const float p = __expf(sv[j][nt] - mi[m][j]);
                    const int off = prow * 128 + ((nt * 32 + fr * 2) ^ ((prow & 7) << 4));
                    *(unsigned short*)((char*)Ps[w] + off) = f2h(p);
                    ps += p;
                }
                li[m][j] += ps;
            }
        }

        // PV: V fragments once, reused by both m-tiles
        half8v vf[4][2];
#pragma unroll
        for (int dt = 0; dt < 4; ++dt) {
            const int d = dt * 16 + fr;
#pragma unroll
            for (int kk = 0; kk < 2; ++kk) {
                const int off = d * 128 + ((kk * 64 + g * 16) ^ ((d & 7) << 4));
                vf[dt][kk] = *(const half8v*)((const char*)Vs[cur] + off);
            }
        }
#pragma unroll
        for (int m = 0; m < 2; ++m) {
            half8v pf[2];
#pragma unroll
            for (int kk = 0; kk < 2; ++kk) {
                const int off = (m * 16 + fr) * 128 + ((kk * 64 + g * 16) ^ ((fr & 7) << 4));
                pf[kk] = *(const half8v*)((const char*)Ps[w] + off);
            }
#pragma unroll
            for (int dt = 0; dt < 4; ++dt)
#pragma unroll
                for (int kk = 0; kk < 2; ++kk)
                    acc[m][dt] = __builtin_amdgcn_mfma_f32_16x16x32_f16(pf[kk], vf[dt][kk], acc[m][dt], 0, 0, 0);
        }

        __syncthreads();   // drains vmcnt(0): next tile staged; cur safe to reuse
        cur ^= 1;
    }

    // final cross-lane li reduce (once), then epilogue
#pragma unroll
    for (int m = 0; m < 2; ++m)
#pragma unroll
        for (int j = 0; j < 4; ++j) {
            float lt = li[m][j];
            lt += __shfl_xor(lt, 1, 64);
            lt += __shfl_xor(lt, 2, 64);
            lt += __shfl_xor(lt, 4, 64);
            lt += __shfl_xor(lt, 8, 64);
            const float inv = 1.f / lt;
            const int t = q0 + w * 32 + m * 16 + 4 * g + j;
            float* op = out + (((size_t)b * NT + t) * NHEADS + h) * HDIM;
#pragma unroll
            for (int dt = 0; dt < 4; ++dt) op[dt * 16 + fr] = acc[m][dt][j] * inv;
        }
}

extern "C" void kernel_launch(void* const* d_in, const int* in_sizes, int n_in,
                              void* d_out, int out_size, void* d_ws, size_t ws_size,
                              hipStream_t stream) {
    const float* x        = (const float*)d_in[0];
    const float* pe_cos   = (const float*)d_in[1];
    const float* pe_sin   = (const float*)d_in[2];
    const float* pe_scale = (const float*)d_in[3];
    const float* mask     = (const float*)d_in[4];
    const float* w_qkv    = (const float*)d_in[5];
    const float* b_qkv    = (const float*)d_in[6];
    float* out = (float*)d_out;

    unsigned short* ws = (unsigned short*)d_ws;
    const size_t PER = (size_t)NB * NHEADS * NT * HDIM;   // 8388608
    unsigned short* qbuf = ws;
    unsigned short* kbuf = ws + PER;
    unsigned short* vtbuf = ws + 2 * PER;
    unsigned short* xbuf = ws + 3 * PER;                  // fp16 x (GEMM only)
    unsigned short* wbuf = xbuf + (size_t)NB * NT * NC;   // fp16 w (GEMM only)
    unsigned short* maskbuf = ws + 3 * PER;               // fp16 mask (after GEMM,
                                                          // reuses x/w region)

    conv_f16_kernel<<<8192, 256, 0, stream>>>(x, xbuf, (NB * NT * NC) / 4);
    conv_f16_kernel<<<3072, 256, 0, stream>>>(w_qkv, wbuf, (3 * NC * NC) / 4);
    qkv_gemm_kernel<<<1536, 256, 0, stream>>>(xbuf, wbuf, b_qkv,
                                              pe_cos, pe_sin, pe_scale,
                                              qbuf, kbuf, vtbuf);
    mask_conv_kernel<<<16384, 256, 0, stream>>>(mask, maskbuf);
    attn_mfma_kernel<<<1024, 256, 0, stream>>>(qbuf, kbuf, vtbuf, maskbuf, out);
}

// Round 10
// 254.797 us; speedup vs baseline: 2.0098x; 1.0230x over previous
//
#include <hip/hip_runtime.h>
#include <math.h>

#define NB 4
#define NT 2048
#define NC 1024
#define NHEADS 16
#define HDIM 64

typedef __attribute__((ext_vector_type(8))) _Float16 half8v;
typedef __attribute__((ext_vector_type(4))) _Float16 half4v;
typedef __attribute__((ext_vector_type(2))) __fp16 fp16x2;
typedef __attribute__((ext_vector_type(4))) float f32x4;

#define LOG2E 1.4426950408889634f

__device__ inline unsigned short f2h(float f) {
    _Float16 h = (_Float16)f;
    return __builtin_bit_cast(unsigned short, h);
}
__device__ inline float h2f(unsigned short u) {
    return (float)__builtin_bit_cast(_Float16, u);
}
__device__ inline float exp2fast(float x) {
#if __has_builtin(__builtin_amdgcn_exp2f)
    return __builtin_amdgcn_exp2f(x);
#else
    return exp2f(x);
#endif
}
__device__ inline unsigned int pack2h(float a, float b) {
    fp16x2 p = __builtin_amdgcn_cvt_pkrtz(a, b);
    return __builtin_bit_cast(unsigned int, p);
}

#define AS1C(p) ((const __attribute__((address_space(1))) unsigned int*)(unsigned long long)(const void*)(p))
#define AS3P(p) ((__attribute__((address_space(3))) unsigned int*)(unsigned int)(unsigned long long)(void*)(p))
#define GLL16(gp, lp) __builtin_amdgcn_global_load_lds(AS1C(gp), AS3P(lp), 16, 0, 0)

// ---------------------------------------------------------------------------
// fp32 -> fp16 convert (vectorized)
// ---------------------------------------------------------------------------
__global__ __launch_bounds__(256) void conv_f16_kernel(
    const float* __restrict__ in, unsigned short* __restrict__ out, int n4)
{
    const int i = blockIdx.x * 256 + threadIdx.x;
    if (i >= n4) return;
    const float4 f = ((const float4*)in)[i];
    ushort4 h;
    h.x = f2h(f.x); h.y = f2h(f.y); h.z = f2h(f.z); h.w = f2h(f.w);
    ((ushort4*)out)[i] = h;
}

// ---------------------------------------------------------------------------
// mask fp32 -> fp16 * log2e, permuted into MFMA fragment order per 64-col
// block: out[row][kt*64 + fr*4 + nt] = in[row][kt*64 + nt*16 + fr] * log2e
// ---------------------------------------------------------------------------
__global__ __launch_bounds__(256) void mask_conv_kernel(
    const float* __restrict__ in, unsigned short* __restrict__ out)
{
    const size_t i = (size_t)blockIdx.x * 256 + threadIdx.x;  // ushort4 index
    const int row = (int)(i >> 9);
    const int c4 = (int)(i & 511);
    const int ktb = c4 >> 4;
    const int fr = c4 & 15;
    const float* ip = in + (size_t)row * NT + ktb * 64 + fr;
    ushort4 o;
    o.x = f2h(ip[0] * LOG2E);
    o.y = f2h(ip[16] * LOG2E);
    o.z = f2h(ip[32] * LOG2E);
    o.w = f2h(ip[48] * LOG2E);
    ((ushort4*)out)[i] = o;
}

// ---------------------------------------------------------------------------
// Kernel 1: qkv = x @ w^T + b via fp16 MFMA, fused RoPE.
// q written fp16 (B,NH,T,D) PRE-SCALED by scl*log2e; k fp16 (B,NH,T,D);
// v written TRANSPOSED+key-PERMUTED fp16: vt2[b][h][d][(t&~63) + pi(t&63)]
// with pi(nt*16+fr) = fr*4+nt, matching attention's P/V k-ordering.
// ---------------------------------------------------------------------------
__global__ __launch_bounds__(256) void qkv_gemm_kernel(
    const unsigned short* __restrict__ xf, const unsigned short* __restrict__ wf,
    const float* __restrict__ bias, const float* __restrict__ pe_cos,
    const float* __restrict__ pe_sin, const float* __restrict__ pe_scale,
    unsigned short* __restrict__ qb, unsigned short* __restrict__ kb,
    unsigned short* __restrict__ vtb)
{
    __shared__ __align__(16) unsigned short Ah[128 * 32];
    __shared__ __align__(16) unsigned short Bh[128 * 32];

    const int tid = threadIdx.x;
    const int w = tid >> 6, lane = tid & 63;
    const int g = lane >> 4, fr = lane & 15;
    const int wr = w >> 1, wc = w & 1;

    const int bid = blockIdx.x;                 // 1536 blocks, XCD swizzle
    const int s = (bid & 7) * 192 + (bid >> 3);
    const int m0 = (s & 63) * 128, n0 = (s >> 6) * 128;

    const int c0 = tid, c1 = tid + 256;
    const int r0 = c0 >> 2, r1 = c1 >> 2;
    const int cb0 = ((c0 & 3) * 16) ^ (((r0 >> 1) & 3) << 4);
    const int cb1 = ((c1 & 3) * 16) ^ (((r1 >> 1) & 3) << 4);
    const unsigned short* px0 = xf + (size_t)(m0 + r0) * NC + (cb0 >> 1);
    const unsigned short* px1 = xf + (size_t)(m0 + r1) * NC + (cb1 >> 1);
    const unsigned short* pw0 = wf + (size_t)(n0 + r0) * NC + (cb0 >> 1);
    const unsigned short* pw1 = wf + (size_t)(n0 + r1) * NC + (cb1 >> 1);

    f32x4 acc[4][4];
#pragma unroll
    for (int m = 0; m < 4; ++m)
#pragma unroll
        for (int n = 0; n < 4; ++n) acc[m][n] = (f32x4){0.f, 0.f, 0.f, 0.f};

    for (int k0 = 0; k0 < NC; k0 += 32) {
        __syncthreads();
        GLL16(px0 + k0, (char*)Ah + c0 * 16);
        GLL16(px1 + k0, (char*)Ah + c1 * 16);
        GLL16(pw0 + k0, (char*)Bh + c0 * 16);
        GLL16(pw1 + k0, (char*)Bh + c1 * 16);
        __syncthreads();

        half8v a_f[4], b_f[4];
#pragma unroll
        for (int m = 0; m < 4; ++m) {
            const int r = wr * 64 + m * 16 + fr;
            const int off = r * 64 + ((g * 16) ^ (((r >> 1) & 3) << 4));
            a_f[m] = *(const half8v*)((const char*)Ah + off);
        }
#pragma unroll
        for (int n = 0; n < 4; ++n) {
            const int r = wc * 64 + n * 16 + fr;
            const int off = r * 64 + ((g * 16) ^ (((r >> 1) & 3) << 4));
            b_f[n] = *(const half8v*)((const char*)Bh + off);
        }
#pragma unroll
        for (int m = 0; m < 4; ++m)
#pragma unroll
            for (int n = 0; n < 4; ++n)
                acc[m][n] = __builtin_amdgcn_mfma_f32_16x16x32_f16(a_f[m], b_f[n], acc[m][n], 0, 0, 0);
    }

    // Epilogue: bias + RoPE (+*scale*scl*log2e q, /scale k), scatter.
    const float QSCL = 0.08838834764831845f * LOG2E;  // 1/sqrt(2*D) * log2e
#pragma unroll
    for (int n = 0; n < 4; ++n) {
        const int col = n0 + wc * 64 + n * 16 + fr;
        const int part = col >> 10;             // wave-uniform (16-col span)
        const int hh = (col & 1023) >> 6;
        const int dd = col & 63;
        const float bv = bias[col];
        if (part < 2) {
            unsigned short* outp = (part == 0) ? qb : kb;
#pragma unroll
            for (int m = 0; m < 4; ++m) {
                const int row0 = m0 + wr * 64 + m * 16 + 4 * g;
                const int bb = row0 >> 11;
                const int t0 = row0 & 2047;
#pragma unroll
                for (int j = 0; j < 4; ++j) {
                    const int t = t0 + j;
                    float val = acc[m][n][j] + bv;
                    const float partner = __shfl_xor(val, 1, 64);
                    const int pidx = t * HDIM + dd;
                    const float cc = pe_cos[pidx], ss = pe_sin[pidx], sc = pe_scale[pidx];
                    const float r = (dd & 1) ? (val * cc + partner * ss)
                                             : (val * cc - partner * ss);
                    val = (part == 0) ? (r * sc * QSCL) : (r / sc);
                    outp[(((size_t)bb * NHEADS + hh) * NT + t) * HDIM + dd] = f2h(val);
                }
            }
        } else {
            // v: key-permuted transpose. Thread holds keys {nt=m, fr'=4g+j}
            // across m -> pos (4g+j)*4 + m are 4 consecutive -> ushort4.
            const int rowb = m0 + wr * 64;       // 64-aligned
            const int bb = rowb >> 11;
            const int tb = rowb & 2047;
            unsigned short* vp2 =
                &vtb[(((size_t)bb * NHEADS + hh) * HDIM + dd) * NT + tb];
#pragma unroll
            for (int j = 0; j < 4; ++j) {
                ushort4 sv;
                sv.x = f2h(acc[0][n][j] + bv);
                sv.y = f2h(acc[1][n][j] + bv);
                sv.z = f2h(acc[2][n][j] + bv);
                sv.w = f2h(acc[3][n][j] + bv);
                *(ushort4*)&vp2[(4 * g + j) * 4] = sv;
            }
        }
    }
}

// ---------------------------------------------------------------------------
// Kernel 2: flash attention, fp16 MFMA. 1 block = (b,h,128 q-rows), 4 waves,
// each wave 32 q-rows (M=2). K/Vt double-buffered (early STAGE issue).
// exp2-folded softmax (q pre-scaled, mask pre-scaled by log2e); key axis of
// P and V consistently pi-permuted -> packed b64 P-writes. Defer-max (T13).
// ---------------------------------------------------------------------------
__global__ __launch_bounds__(256) void attn_mfma_kernel(
    const unsigned short* __restrict__ qb, const unsigned short* __restrict__ kb,
    const unsigned short* __restrict__ vtb, const unsigned short* __restrict__ m16,
    float* __restrict__ out)
{
    __shared__ __align__(16) unsigned short Ks[2][64 * 64];
    __shared__ __align__(16) unsigned short Vs[2][64 * 64];
    __shared__ __align__(16) unsigned short Ps[4][32 * 64];

    const int tid = threadIdx.x;
    const int w = tid >> 6, lane = tid & 63;
    const int g = lane >> 4, fr = lane & 15;

    const int bid = blockIdx.x;                  // 1024 blocks, XCD swizzle
    const int s = (bid & 7) * 128 + (bid >> 3);
    const int q0 = (s & 15) * 128;
    const int h = (s >> 4) & 15;
    const int b = s >> 8;

    const size_t bh = (size_t)b * NHEADS + h;
    const unsigned short* qp = qb + (bh * NT + q0 + w * 32) * HDIM;
    const unsigned short* kp = kb + bh * NT * HDIM;
    const unsigned short* vtp = vtb + bh * HDIM * NT;
    const unsigned short* mp = m16 + ((size_t)b * NT + q0 + w * 32) * NT;

    const int sc0 = tid, sc1 = tid + 256;
    const int sr0 = sc0 >> 3, scb0 = ((sc0 & 7) * 16) ^ ((sr0 & 7) << 4);
    const int sr1 = sc1 >> 3, scb1 = ((sc1 & 7) * 16) ^ ((sr1 & 7) << 4);

#define STAGE(buf, kt)                                                          \
    do {                                                                        \
        const unsigned short* ktp_ = kp + (kt) * 64 * HDIM;                     \
        GLL16(ktp_ + sr0 * HDIM + (scb0 >> 1), (char*)Ks[buf] + sc0 * 16);      \
        GLL16(vtp + (size_t)sr0 * NT + (kt) * 64 + (scb0 >> 1),                 \
              (char*)Vs[buf] + sc0 * 16);                                       \
        GLL16(ktp_ + sr1 * HDIM + (scb1 >> 1), (char*)Ks[buf] + sc1 * 16);      \
        GLL16(vtp + (size_t)sr1 * NT + (kt) * 64 + (scb1 >> 1),                 \
              (char*)Vs[buf] + sc1 * 16);                                       \
    } while (0)

    half8v qf[2][2];
#pragma unroll
    for (int m = 0; m < 2; ++m)
#pragma unroll
        for (int kk = 0; kk < 2; ++kk)
            qf[m][kk] = *(const half8v*)(qp + (m * 16 + fr) * HDIM + kk * 32 + g * 8);

    f32x4 acc[2][4];
    float li[2][4], mi[2][4];
#pragma unroll
    for (int m = 0; m < 2; ++m)
#pragma unroll
        for (int j = 0; j < 4; ++j) {
            li[m][j] = 0.f; mi[m][j] = -3.0e38f;
            acc[m][j] = (f32x4){0.f, 0.f, 0.f, 0.f};
        }
    const float THR = 11.541560327111708f;   // 8 * log2e

    STAGE(0, 0);
    __syncthreads();
    int cur = 0;

    for (int kt = 0; kt < NT / 64; ++kt) {
        if (kt + 1 < NT / 64) STAGE(cur ^ 1, kt + 1);

        half8v kf[4][2];
#pragma unroll
        for (int nt = 0; nt < 4; ++nt) {
            const int r = nt * 16 + fr;
#pragma unroll
            for (int kk = 0; kk < 2; ++kk) {
                const int off = r * 128 + ((kk * 64 + g * 16) ^ ((r & 7) << 4));
                kf[nt][kk] = *(const half8v*)((const char*)Ks[cur] + off);
            }
        }

#pragma unroll
        for (int m = 0; m < 2; ++m) {
            f32x4 Sm[4];
#pragma unroll
            for (int nt = 0; nt < 4; ++nt) {
                Sm[nt] = (f32x4){0.f, 0.f, 0.f, 0.f};
#pragma unroll
                for (int kk = 0; kk < 2; ++kk)
                    Sm[nt] = __builtin_amdgcn_mfma_f32_16x16x32_f16(qf[m][kk], kf[nt][kk], Sm[nt], 0, 0, 0);
            }

            float sv[4][4], rmj[4];
#pragma unroll
            for (int j = 0; j < 4; ++j) {
                const ushort4 mv = *(const ushort4*)(
                    mp + (size_t)(m * 16 + 4 * g + j) * NT + kt * 64 + fr * 4);
                sv[j][0] = Sm[0][j] + h2f(mv.x);
                sv[j][1] = Sm[1][j] + h2f(mv.y);
                sv[j][2] = Sm[2][j] + h2f(mv.z);
                sv[j][3] = Sm[3][j] + h2f(mv.w);
                rmj[j] = fmaxf(fmaxf(sv[j][0], sv[j][1]), fmaxf(sv[j][2], sv[j][3]));
            }

            const float worst = fmaxf(fmaxf(rmj[0] - mi[m][0], rmj[1] - mi[m][1]),
                                      fmaxf(rmj[2] - mi[m][2], rmj[3] - mi[m][3]));
            if (!__all(worst <= THR)) {
#pragma unroll
                for (int j = 0; j < 4; ++j) {
                    float rm = rmj[j];
                    rm = fmaxf(rm, __shfl_xor(rm, 1, 64));
                    rm = fmaxf(rm, __shfl_xor(rm, 2, 64));
                    rm = fmaxf(rm, __shfl_xor(rm, 4, 64));
                    rm = fmaxf(rm, __shfl_xor(rm, 8, 64));
                    const float mnew = fmaxf(mi[m][j], rm);
                    const float alpha = exp2fast(mi[m][j] - mnew);
                    li[m][j] *= alpha;
#pragma unroll
                    for (int dt = 0; dt < 4; ++dt) acc[m][dt][j] *= alpha;
                    mi[m][j] = mnew;
                }
            }

#pragma unroll
            for (int j = 0; j < 4; ++j) {
                const int prow = m * 16 + 4 * g + j;
                const float p0 = exp2fast(sv[j][0] - mi[m][j]);
                const float p1 = exp2fast(sv[j][1] - mi[m][j]);
                const float p2 = exp2fast(sv[j][2] - mi[m][j]);
                const float p3 = exp2fast(sv[j][3] - mi[m][j]);
                li[m][j] += (p0 + p1) + (p2 + p3);
                uint2 pw2;
                pw2.x = pack2h(p0, p1);
                pw2.y = pack2h(p2, p3);
                const int off = prow * 128 + ((fr * 8) ^ ((prow & 7) << 4));
                *(uint2*)((char*)Ps[w] + off) = pw2;
            }
        }

        half8v vf[4][2];
#pragma unroll
        for (int dt = 0; dt < 4; ++dt) {
            const int d = dt * 16 + fr;
#pragma unroll
            for (int kk = 0; kk < 2; ++kk) {
                const int off = d * 128 + ((kk * 64 + g * 16) ^ ((d & 7) << 4));
                vf[dt][kk] = *(const half8v*)((const char*)Vs[cur] + off);
            }
        }
#pragma unroll
        for (int m = 0; m < 2; ++m) {
            half8v pf[2];
#pragma unroll
            for (int kk = 0; kk < 2; ++kk) {
                const int off = (m * 16 + fr) * 128 + ((kk * 64 + g * 16) ^ ((fr & 7) << 4));
                pf[kk] = *(const half8v*)((const char*)Ps[w] + off);
            }
#pragma unroll
            for (int dt = 0; dt < 4; ++dt)
#pragma unroll
                for (int kk = 0; kk < 2; ++kk)
                    acc[m][dt] = __builtin_amdgcn_mfma_f32_16x16x32_f16(pf[kk], vf[dt][kk], acc[m][dt], 0, 0, 0);
        }

        __syncthreads();
        cur ^= 1;
    }

#pragma unroll
    for (int m = 0; m < 2; ++m)
#pragma unroll
        for (int j = 0; j < 4; ++j) {
            float lt = li[m][j];
            lt += __shfl_xor(lt, 1, 64);
            lt += __shfl_xor(lt, 2, 64);
            lt += __shfl_xor(lt, 4, 64);
            lt += __shfl_xor(lt, 8, 64);
            const float inv = 1.f / lt;
            const int t = q0 + w * 32 + m * 16 + 4 * g + j;
            float* op = out + (((size_t)b * NT + t) * NHEADS + h) * HDIM;
#pragma unroll
            for (int dt = 0; dt < 4; ++dt) op[dt * 16 + fr] = acc[m][dt][j] * inv;
        }
}

extern "C" void kernel_launch(void* const* d_in, const int* in_sizes, int n_in,
                              void* d_out, int out_size, void* d_ws, size_t ws_size,
                              hipStream_t stream) {
    const float* x        = (const float*)d_in[0];
    const float* pe_cos   = (const float*)d_in[1];
    const float* pe_sin   = (const float*)d_in[2];
    const float* pe_scale = (const float*)d_in[3];
    const float* mask     = (const float*)d_in[4];
    const float* w_qkv    = (const float*)d_in[5];
    const float* b_qkv    = (const float*)d_in[6];
    float* out = (float*)d_out;

    unsigned short* ws = (unsigned short*)d_ws;
    const size_t PER = (size_t)NB * NHEADS * NT * HDIM;   // 8388608
    unsigned short* qbuf = ws;
    unsigned short* kbuf = ws + PER;
    unsigned short* vtbuf = ws + 2 * PER;
    unsigned short* xbuf = ws + 3 * PER;                  // fp16 x (GEMM only)
    unsigned short* wbuf = xbuf + (size_t)NB * NT * NC;   // fp16 w (GEMM only)
    unsigned short* maskbuf = ws + 3 * PER;               // fp16 mask (after GEMM)

    conv_f16_kernel<<<8192, 256, 0, stream>>>(x, xbuf, (NB * NT * NC) / 4);
    conv_f16_kernel<<<3072, 256, 0, stream>>>(w_qkv, wbuf, (3 * NC * NC) / 4);
    qkv_gemm_kernel<<<1536, 256, 0, stream>>>(xbuf, wbuf, b_qkv,
                                              pe_cos, pe_sin, pe_scale,
                                              qbuf, kbuf, vtbuf);
    mask_conv_kernel<<<16384, 256, 0, stream>>>(mask, maskbuf);
    attn_mfma_kernel<<<1024, 256, 0, stream>>>(qbuf, kbuf, vtbuf, maskbuf, out);
}